// Round 2
// baseline (1003.361 us; speedup 1.0000x reference)
//
#include <hip/hip_runtime.h>
#include <math.h>

// Shapes (fixed by the problem)
#define BATCH 2
#define SEQ   2048
#define NH    12
#define HD    64
#define EMB   768      // NH*HD
#define PLM   1280
#define FFN   640
#define MROWS (BATCH*SEQ)   // 4096

typedef __attribute__((ext_vector_type(8))) short short8;   // 8 bf16
typedef __attribute__((ext_vector_type(4))) float floatx4;

#define MFMA16(a,b,c) __builtin_amdgcn_mfma_f32_16x16x32_bf16((a),(b),(c),0,0,0)

static __device__ __forceinline__ float b2f(ushort u) {
    return __uint_as_float(((unsigned)u) << 16);
}
static __device__ __forceinline__ ushort f2b(float f) {
    unsigned x = __float_as_uint(f);
    unsigned r = (x + 0x7fffu + ((x >> 16) & 1u)) >> 16;   // RNE, finite inputs
    return (ushort)r;
}

// ---------------------------------------------------------------------------
// f32 -> bf16 conversion prepass (vectorized 4 elems/thread)
// ---------------------------------------------------------------------------
__global__ __launch_bounds__(256) void cvt_kernel(
    const float* __restrict__ in, ushort* __restrict__ out, int n4)
{
    int i = blockIdx.x * blockDim.x + threadIdx.x;
    if (i < n4) {
        float4 v = ((const float4*)in)[i];
        ushort4 o;
        o.x = f2b(v.x); o.y = f2b(v.y); o.z = f2b(v.z); o.w = f2b(v.w);
        ((ushort4*)out)[i] = o;
    }
}

// ---------------------------------------------------------------------------
// Generic NT GEMM: C[m,n] = sum_k A[m,k] * W[n,k]  (+ epilogue)
// A, W are bf16 (pre-converted). bias is f32. Block tile 64x64, 4 waves.
// EPI: 1 = bias + RoPE -> bf16 [B,H,S,D]  (q,k; one N-tile == one head)
//      2 = bias -> bf16 transposed [B,H,D,S] (v)
//      3 = bias + f32-residual add -> bf16 row-major (x = o + plm)
//      4 = bias + exact GELU -> bf16 row-major (h)
//      5 = bias + bf16-residual add -> f32 row-major (final out)
// ---------------------------------------------------------------------------
template<int EPI>
__global__ __launch_bounds__(256, 2) void gemm_nt(
    const ushort* __restrict__ A,      // [M,K] bf16
    const ushort* __restrict__ W,      // [N,K] bf16
    const float*  __restrict__ bias,   // [N]   f32
    const float*  __restrict__ residF, // [M,N] f32  (EPI==3)
    const ushort* __restrict__ residB, // [M,N] bf16 (EPI==5)
    void* __restrict__ out_,
    int M, int N, int K)
{
    const int tid  = threadIdx.x;
    const int wave = tid >> 6;
    const int lane = tid & 63;
    const int quad = lane >> 4;
    const int col  = lane & 15;
    const int m0   = blockIdx.x * 64 + wave * 16;
    const int n0   = blockIdx.y * 64;

    const ushort* arow = A + (size_t)(m0 + col) * K + quad * 8;
    const ushort* wrow = W + (size_t)(n0 + col) * K + quad * 8;
    const size_t  wstep = (size_t)16 * K;

    const floatx4 zero = {0.f, 0.f, 0.f, 0.f};
    floatx4 acc[4] = {zero, zero, zero, zero};

    for (int k0 = 0; k0 < K; k0 += 32) {
        short8 a = *(const short8*)(arow + k0);
#pragma unroll
        for (int f = 0; f < 4; ++f) {
            short8 b = *(const short8*)(wrow + (size_t)f * wstep + k0);
            acc[f] = MFMA16(a, b, acc[f]);
        }
    }

    float bs[4];
#pragma unroll
    for (int f = 0; f < 4; ++f) bs[f] = bias[n0 + f * 16 + col];

    if constexpr (EPI == 1) {
        // bias + RoPE, store bf16 [B, H, S, D]; head h = n0/64, d = f*16+col
        ushort* out = (ushort*)out_;
        const int h = n0 >> 6;
#pragma unroll
        for (int r = 0; r < 4; ++r) {
            int m = m0 + quad * 4 + r;
            int b = m >> 11, s = m & (SEQ - 1);
            size_t obase = ((size_t)(b * NH + h) * SEQ + s) * HD;
#pragma unroll
            for (int f = 0; f < 2; ++f) {
                int d = f * 16 + col;                 // 0..31
                float x1 = acc[f][r] + bs[f];
                float x2 = acc[f + 2][r] + bs[f + 2];
                float invf = __expf((float)d * -0.2878231366242557f); // 10000^(-d/32)
                float theta = (float)s * invf;
                float sn, cs;
                sincosf(theta, &sn, &cs);
                out[obase + d]      = f2b(x1 * cs - x2 * sn);
                out[obase + d + 32] = f2b(x2 * cs + x1 * sn);
            }
        }
    } else if constexpr (EPI == 2) {
        // bias, store bf16 transposed [B, H, D, S]
        ushort* out = (ushort*)out_;
        const int h = n0 >> 6;
#pragma unroll
        for (int r = 0; r < 4; ++r) {
            int m = m0 + quad * 4 + r;
            int b = m >> 11, s = m & (SEQ - 1);
#pragma unroll
            for (int f = 0; f < 4; ++f) {
                int d = f * 16 + col;
                out[((size_t)(b * NH + h) * HD + d) * SEQ + s] = f2b(acc[f][r] + bs[f]);
            }
        }
    } else if constexpr (EPI == 3) {
        // bias + f32 residual, bf16 row-major
        ushort* out = (ushort*)out_;
#pragma unroll
        for (int r = 0; r < 4; ++r) {
            int m = m0 + quad * 4 + r;
#pragma unroll
            for (int f = 0; f < 4; ++f) {
                size_t idx = (size_t)m * N + n0 + f * 16 + col;
                out[idx] = f2b(acc[f][r] + bs[f] + residF[idx]);
            }
        }
    } else if constexpr (EPI == 4) {
        // bias + exact GELU, bf16 row-major
        ushort* out = (ushort*)out_;
#pragma unroll
        for (int r = 0; r < 4; ++r) {
            int m = m0 + quad * 4 + r;
#pragma unroll
            for (int f = 0; f < 4; ++f) {
                size_t idx = (size_t)m * N + n0 + f * 16 + col;
                float y = acc[f][r] + bs[f];
                out[idx] = f2b(0.5f * y * (1.0f + erff(y * 0.70710678118654752f)));
            }
        }
    } else {
        // EPI == 5: bias + bf16 residual, f32 row-major (final output)
        float* out = (float*)out_;
#pragma unroll
        for (int r = 0; r < 4; ++r) {
            int m = m0 + quad * 4 + r;
#pragma unroll
            for (int f = 0; f < 4; ++f) {
                size_t idx = (size_t)m * N + n0 + f * 16 + col;
                out[idx] = acc[f][r] + bs[f] + b2f(residB[idx]);
            }
        }
    }
}

// ---------------------------------------------------------------------------
// Attention: per block (qt, bh): 64 q-rows x full 2048 kv.
// q [B,H,S,D] bf16, k [B,H,S,D] bf16 (RoPE'd), v [B,H,D,S] bf16.
// Pass 1: row sums of exp(qk/8) (no max-sub; logits bounded ~|5|).
// Pass 2: recompute, normalize, write f32 attention probs directly, and
// P@V via bf16 LDS round-trip (per-wave private tile, no barrier needed).
// ---------------------------------------------------------------------------
__global__ __launch_bounds__(256, 2) void attn_kernel(
    const ushort* __restrict__ qb, const ushort* __restrict__ kb,
    const ushort* __restrict__ vb,
    float* __restrict__ attn_out,    // [B,H,S,S] f32
    ushort* __restrict__ vals)       // [B*S, EMB] bf16
{
    const int qt   = blockIdx.x;     // 0..31
    const int bh   = blockIdx.y;     // 0..23
    const int tid  = threadIdx.x;
    const int wave = tid >> 6;
    const int lane = tid & 63;
    const int quad = lane >> 4;
    const int col  = lane & 15;

    __shared__ __align__(16) ushort P[4][16 * 64];  // per-wave private 16x64 tile

    const floatx4 zero = {0.f, 0.f, 0.f, 0.f};

    // q fragments for this wave's 16 rows, kept in registers for both passes
    const ushort* qrow = qb + ((size_t)bh * SEQ + qt * 64 + wave * 16 + col) * HD + quad * 8;
    short8 aq0 = *(const short8*)qrow;
    short8 aq1 = *(const short8*)(qrow + 32);

    const ushort* kbase = kb + (size_t)bh * SEQ * HD + (size_t)col * HD + quad * 8;
    const ushort* vbase = vb + (size_t)bh * HD * SEQ + (size_t)col * SEQ + quad * 8;

    // ---- pass 1: row sums of exp ----
    float sums[4] = {0.f, 0.f, 0.f, 0.f};
    for (int ch = 0; ch < 32; ++ch) {
#pragma unroll
        for (int f = 0; f < 4; ++f) {
            const ushort* kr = kbase + (size_t)(ch * 64 + f * 16) * HD;
            short8 b0 = *(const short8*)kr;
            short8 b1 = *(const short8*)(kr + 32);
            floatx4 t = MFMA16(aq0, b0, zero);
            t = MFMA16(aq1, b1, t);
#pragma unroll
            for (int r = 0; r < 4; ++r) sums[r] += __expf(t[r] * 0.125f);
        }
    }
    // reduce across the 16 lanes of each quad-group (cols), keep 1/sum
#pragma unroll
    for (int r = 0; r < 4; ++r) {
        float v = sums[r];
        v += __shfl_xor(v, 1); v += __shfl_xor(v, 2);
        v += __shfl_xor(v, 4); v += __shfl_xor(v, 8);
        sums[r] = 1.0f / v;
    }

    // ---- pass 2: normalize + emit f32 attention + P@V ----
    const size_t arow0 = (size_t)(bh * SEQ + qt * 64 + wave * 16);
    floatx4 acco[4] = {zero, zero, zero, zero};
    for (int ch = 0; ch < 32; ++ch) {
#pragma unroll
        for (int f = 0; f < 4; ++f) {
            const ushort* kr = kbase + (size_t)(ch * 64 + f * 16) * HD;
            short8 b0 = *(const short8*)kr;
            short8 b1 = *(const short8*)(kr + 32);
            floatx4 t = MFMA16(aq0, b0, zero);
            t = MFMA16(aq1, b1, t);
#pragma unroll
            for (int r = 0; r < 4; ++r) {
                float p = __expf(t[r] * 0.125f) * sums[r];
                P[wave][(quad * 4 + r) * 64 + f * 16 + col] = f2b(p);
                attn_out[(arow0 + quad * 4 + r) * SEQ + ch * 64 + f * 16 + col] = p;
            }
        }

        // P (A-layout from LDS, per-wave private) @ V^T fragments
        const ushort* pl = &P[wave][col * 64 + quad * 8];
        short8 ap0 = *(const short8*)pl;
        short8 ap1 = *(const short8*)(pl + 32);
#pragma unroll
        for (int f = 0; f < 4; ++f) {
            const ushort* vr = vbase + (size_t)(f * 16) * SEQ + ch * 64;
            short8 b0 = *(const short8*)vr;
            short8 b1 = *(const short8*)(vr + 32);
            acco[f] = MFMA16(ap0, b0, acco[f]);
            acco[f] = MFMA16(ap1, b1, acco[f]);
        }
    }

    // write vals as bf16 row-major [B*S, EMB] (ready for the Wo NT GEMM)
    const int b = bh / NH, h = bh - b * NH;
#pragma unroll
    for (int f = 0; f < 4; ++f) {
#pragma unroll
        for (int r = 0; r < 4; ++r) {
            int srow = qt * 64 + wave * 16 + quad * 4 + r;
            size_t idx = ((size_t)(b * SEQ + srow)) * EMB + h * HD + f * 16 + col;
            vals[idx] = f2b(acco[f][r]);
        }
    }
}

// ---------------------------------------------------------------------------
// LayerNorm over 1280, one block (256 threads) per row.
// x bf16 in, gamma/beta f32, bf16 out.
// ---------------------------------------------------------------------------
__global__ __launch_bounds__(256) void ln_kernel(
    const ushort* __restrict__ x, const float* __restrict__ g,
    const float* __restrict__ bt, ushort* __restrict__ out)
{
    const int row = blockIdx.x;
    const int tid = threadIdx.x;
    const ushort* xr = x + (size_t)row * PLM;

    float xs[5];
    float s = 0.f, s2 = 0.f;
#pragma unroll
    for (int i = 0; i < 5; ++i) {
        float v = b2f(xr[tid + i * 256]);
        xs[i] = v; s += v; s2 += v * v;
    }
#pragma unroll
    for (int off = 1; off < 64; off <<= 1) {
        s  += __shfl_xor(s,  off);
        s2 += __shfl_xor(s2, off);
    }
    __shared__ float red[8];
    const int wave = tid >> 6, lane = tid & 63;
    if (lane == 0) { red[wave] = s; red[4 + wave] = s2; }
    __syncthreads();
    s  = red[0] + red[1] + red[2] + red[3];
    s2 = red[4] + red[5] + red[6] + red[7];
    float mean = s * (1.0f / PLM);
    float var  = s2 * (1.0f / PLM) - mean * mean;
    float rstd = rsqrtf(var + 1e-5f);

    ushort* orow = out + (size_t)row * PLM;
#pragma unroll
    for (int i = 0; i < 5; ++i) {
        int c = tid + i * 256;
        orow[c] = f2b((xs[i] - mean) * rstd * g[c] + bt[c]);
    }
}

// ---------------------------------------------------------------------------
extern "C" void kernel_launch(void* const* d_in, const int* in_sizes, int n_in,
                              void* d_out, int out_size, void* d_ws, size_t ws_size,
                              hipStream_t stream)
{
    const float* s_repre = (const float*)d_in[0];   // [2,2048,128]
    const float* plm     = (const float*)d_in[1];   // [2,2048,1280]
    const float* Wq = (const float*)d_in[2];
    const float* bq = (const float*)d_in[3];
    const float* Wk = (const float*)d_in[4];
    const float* bk = (const float*)d_in[5];
    const float* Wv = (const float*)d_in[6];
    const float* bv = (const float*)d_in[7];
    const float* Wo = (const float*)d_in[8];
    const float* bo = (const float*)d_in[9];
    const float* ln_g = (const float*)d_in[10];
    const float* ln_b = (const float*)d_in[11];
    const float* Wd = (const float*)d_in[12];
    const float* bd = (const float*)d_in[13];
    const float* Wu = (const float*)d_in[14];
    const float* bu = (const float*)d_in[15];

    // workspace layout (bf16 elements)
    ushort* ws    = (ushort*)d_ws;
    ushort* q_buf = ws;                          // [B,H,S,D]
    ushort* k_buf = q_buf + (size_t)MROWS * EMB;
    ushort* v_buf = k_buf + (size_t)MROWS * EMB; // [B,H,D,S]
    ushort* vals  = v_buf + (size_t)MROWS * EMB; // [B*S, EMB]
    ushort* x_buf = vals  + (size_t)MROWS * EMB; // [B*S, PLM]
    ushort* resid = x_buf + (size_t)MROWS * PLM; // [B*S, PLM]
    ushort* h_buf = resid + (size_t)MROWS * PLM; // [B*S, FFN]
    // bf16 copies of f32 inputs
    ushort* sr_b  = h_buf + (size_t)MROWS * FFN;
    ushort* plm_b = sr_b  + (size_t)MROWS * 128;
    ushort* Wq_b  = plm_b + (size_t)MROWS * PLM;
    ushort* Wk_b  = Wq_b  + (size_t)EMB * PLM;
    ushort* Wv_b  = Wk_b  + (size_t)EMB * 128;
    ushort* Wo_b  = Wv_b  + (size_t)EMB * 128;
    ushort* Wd_b  = Wo_b  + (size_t)PLM * EMB;
    ushort* Wu_b  = Wd_b  + (size_t)FFN * PLM;

    float* out_main = (float*)d_out;                        // [B*S, PLM]
    float* attn_out = out_main + (size_t)MROWS * PLM;       // [B,H,S,S]

    dim3 blk(256);
    auto cvt = [&](const float* src, ushort* dst, size_t n) {
        int n4 = (int)(n / 4);
        cvt_kernel<<<dim3((n4 + 255) / 256), blk, 0, stream>>>(src, dst, n4);
    };

    cvt(s_repre, sr_b,  (size_t)MROWS * 128);
    cvt(plm,     plm_b, (size_t)MROWS * PLM);
    cvt(Wq, Wq_b, (size_t)EMB * PLM);
    cvt(Wk, Wk_b, (size_t)EMB * 128);
    cvt(Wv, Wv_b, (size_t)EMB * 128);
    cvt(Wo, Wo_b, (size_t)PLM * EMB);
    cvt(Wd, Wd_b, (size_t)FFN * PLM);
    cvt(Wu, Wu_b, (size_t)PLM * FFN);

    // q = RoPE(plm @ Wq^T + bq)            -> [B,H,S,D]
    gemm_nt<1><<<dim3(MROWS / 64, EMB / 64), blk, 0, stream>>>(
        plm_b, Wq_b, bq, nullptr, nullptr, q_buf, MROWS, EMB, PLM);
    // k = RoPE(s_repre @ Wk^T + bk)        -> [B,H,S,D]
    gemm_nt<1><<<dim3(MROWS / 64, EMB / 64), blk, 0, stream>>>(
        sr_b, Wk_b, bk, nullptr, nullptr, k_buf, MROWS, EMB, 128);
    // v = s_repre @ Wv^T + bv              -> [B,H,D,S]
    gemm_nt<2><<<dim3(MROWS / 64, EMB / 64), blk, 0, stream>>>(
        sr_b, Wv_b, bv, nullptr, nullptr, v_buf, MROWS, EMB, 128);

    // attention probs (f32, to d_out) + vals (bf16)
    attn_kernel<<<dim3(SEQ / 64, BATCH * NH), blk, 0, stream>>>(
        q_buf, k_buf, v_buf, attn_out, vals);

    // x = vals @ Wo^T + bo + plm           -> x_buf (bf16)
    gemm_nt<3><<<dim3(MROWS / 64, PLM / 64), blk, 0, stream>>>(
        vals, Wo_b, bo, plm, nullptr, x_buf, MROWS, PLM, EMB);

    // resid = LayerNorm(x)
    ln_kernel<<<dim3(MROWS), blk, 0, stream>>>(x_buf, ln_g, ln_b, resid);

    // h = gelu(resid @ Wd^T + bd)
    gemm_nt<4><<<dim3(MROWS / 64, FFN / 64), blk, 0, stream>>>(
        resid, Wd_b, bd, nullptr, nullptr, h_buf, MROWS, FFN, PLM);

    // out = h @ Wu^T + bu + resid          -> d_out (f32)
    gemm_nt<5><<<dim3(MROWS / 64, PLM / 64), blk, 0, stream>>>(
        h_buf, Wu_b, bu, nullptr, resid, out_main, MROWS, PLM, FFN);
}

// Round 3
// 959.963 us; speedup vs baseline: 1.0452x; 1.0452x over previous
//
#include <hip/hip_runtime.h>
#include <hip/hip_bf16.h>
#include <math.h>

// Shapes (fixed by the problem)
#define BATCH 2
#define SEQ   2048
#define NH    12
#define HD    64
#define EMB   768      // NH*HD
#define PLM   1280
#define FFN   640
#define MROWS (BATCH*SEQ)   // 4096

typedef __attribute__((ext_vector_type(8))) short short8;   // 8 bf16
typedef __attribute__((ext_vector_type(4))) float floatx4;

#define MFMA16(a,b,c) __builtin_amdgcn_mfma_f32_16x16x32_bf16((a),(b),(c),0,0,0)

static __device__ __forceinline__ float b2f(ushort u) {
    return __uint_as_float(((unsigned)u) << 16);
}
static __device__ __forceinline__ ushort f2b(float f) {
    unsigned x = __float_as_uint(f);
    unsigned r = (x + 0x7fffu + ((x >> 16) & 1u)) >> 16;   // RNE, finite inputs
    return (ushort)r;
}
// packed f32x2 -> bf16x2 (v_cvt_pk_bf16_f32)
static __device__ __forceinline__ ushort2 f2b2(float a, float b) {
    __hip_bfloat162 h = __float22bfloat162_rn(make_float2(a, b));
    union { __hip_bfloat162 h2; ushort2 u2; } c; c.h2 = h;
    return c.u2;
}

// ---------------------------------------------------------------------------
// Fused f32 -> bf16 conversion for all 8 inputs (dsts contiguous in ws).
// All segment vec4-counts are multiples of 256, so each block is uniform.
// ---------------------------------------------------------------------------
#define CV0 131072     // s_repre  (2*2048*128 /4)
#define CV1 1441792    // + plm    (2*2048*1280/4)
#define CV2 1687552    // + Wq     (768*1280/4)
#define CV3 1712128    // + Wk     (768*128/4)
#define CV4 1736704    // + Wv
#define CV5 1982464    // + Wo     (1280*768/4)
#define CV6 2187264    // + Wd     (640*1280/4)
#define CV7 2392064    // + Wu     (1280*640/4)

__global__ __launch_bounds__(256) void cvt_all(
    const float* __restrict__ s0, const float* __restrict__ s1,
    const float* __restrict__ s2, const float* __restrict__ s3,
    const float* __restrict__ s4, const float* __restrict__ s5,
    const float* __restrict__ s6, const float* __restrict__ s7,
    ushort* __restrict__ dst)
{
    int i = blockIdx.x * 256 + threadIdx.x;     // vec4 index
    const float* src; int start;
    if      (i < CV0) { src = s0; start = 0;   }
    else if (i < CV1) { src = s1; start = CV0; }
    else if (i < CV2) { src = s2; start = CV1; }
    else if (i < CV3) { src = s3; start = CV2; }
    else if (i < CV4) { src = s4; start = CV3; }
    else if (i < CV5) { src = s5; start = CV4; }
    else if (i < CV6) { src = s6; start = CV5; }
    else              { src = s7; start = CV6; }
    float4 v = ((const float4*)src)[i - start];
    ushort2 a = f2b2(v.x, v.y), b = f2b2(v.z, v.w);
    ushort4 o; o.x = a.x; o.y = a.y; o.z = b.x; o.w = b.y;
    ((ushort4*)dst)[i] = o;
}

// ---------------------------------------------------------------------------
// Generic NT GEMM: C[m,n] = sum_k A[m,k] * W[n,k]  (+ epilogue)
// A, W bf16; bias f32. Block tile 64x64, 4 waves; k unrolled by 64.
// EPI: 1 = bias + RoPE -> bf16 [B,H,S,D]
//      2 = bias -> bf16 transposed [B,H,D,S]
//      3 = bias + f32-residual add -> bf16 row-major
//      4 = bias + exact GELU -> bf16 row-major
//      5 = bias + bf16-residual add -> f32 row-major (final out)
// ---------------------------------------------------------------------------
template<int EPI>
__global__ __launch_bounds__(256, 2) void gemm_nt(
    const ushort* __restrict__ A,      // [M,K] bf16
    const ushort* __restrict__ W,      // [N,K] bf16
    const float*  __restrict__ bias,   // [N]   f32
    const float*  __restrict__ residF, // [M,N] f32  (EPI==3)
    const ushort* __restrict__ residB, // [M,N] bf16 (EPI==5)
    void* __restrict__ out_,
    int M, int N, int K)
{
    const int tid  = threadIdx.x;
    const int wave = tid >> 6;
    const int lane = tid & 63;
    const int quad = lane >> 4;
    const int col  = lane & 15;
    const int m0   = blockIdx.x * 64 + wave * 16;
    const int n0   = blockIdx.y * 64;

    const ushort* arow = A + (size_t)(m0 + col) * K + quad * 8;
    const ushort* wrow = W + (size_t)(n0 + col) * K + quad * 8;
    const size_t  wstep = (size_t)16 * K;

    const floatx4 zero = {0.f, 0.f, 0.f, 0.f};
    floatx4 acc[4] = {zero, zero, zero, zero};

    for (int k0 = 0; k0 < K; k0 += 64) {
        short8 a0 = *(const short8*)(arow + k0);
        short8 a1 = *(const short8*)(arow + k0 + 32);
        short8 b[8];
#pragma unroll
        for (int f = 0; f < 4; ++f) {
            b[2 * f]     = *(const short8*)(wrow + (size_t)f * wstep + k0);
            b[2 * f + 1] = *(const short8*)(wrow + (size_t)f * wstep + k0 + 32);
        }
#pragma unroll
        for (int f = 0; f < 4; ++f) {
            acc[f] = MFMA16(a0, b[2 * f], acc[f]);
            acc[f] = MFMA16(a1, b[2 * f + 1], acc[f]);
        }
    }

    float bs[4];
#pragma unroll
    for (int f = 0; f < 4; ++f) bs[f] = bias[n0 + f * 16 + col];

    if constexpr (EPI == 1) {
        ushort* out = (ushort*)out_;
        const int h = n0 >> 6;
#pragma unroll
        for (int r = 0; r < 4; ++r) {
            int m = m0 + quad * 4 + r;
            int b_ = m >> 11, s = m & (SEQ - 1);
            size_t obase = ((size_t)(b_ * NH + h) * SEQ + s) * HD;
#pragma unroll
            for (int f = 0; f < 2; ++f) {
                int d = f * 16 + col;                 // 0..31
                float x1 = acc[f][r] + bs[f];
                float x2 = acc[f + 2][r] + bs[f + 2];
                float invf = __expf((float)d * -0.2878231366242557f); // 10000^(-d/32)
                float theta = (float)s * invf;
                float sn, cs;
                sincosf(theta, &sn, &cs);
                out[obase + d]      = f2b(x1 * cs - x2 * sn);
                out[obase + d + 32] = f2b(x2 * cs + x1 * sn);
            }
        }
    } else if constexpr (EPI == 2) {
        ushort* out = (ushort*)out_;
        const int h = n0 >> 6;
#pragma unroll
        for (int r = 0; r < 4; ++r) {
            int m = m0 + quad * 4 + r;
            int b_ = m >> 11, s = m & (SEQ - 1);
#pragma unroll
            for (int f = 0; f < 4; ++f) {
                int d = f * 16 + col;
                out[((size_t)(b_ * NH + h) * HD + d) * SEQ + s] = f2b(acc[f][r] + bs[f]);
            }
        }
    } else if constexpr (EPI == 3) {
        ushort* out = (ushort*)out_;
#pragma unroll
        for (int r = 0; r < 4; ++r) {
            int m = m0 + quad * 4 + r;
#pragma unroll
            for (int f = 0; f < 4; ++f) {
                size_t idx = (size_t)m * N + n0 + f * 16 + col;
                out[idx] = f2b(acc[f][r] + bs[f] + residF[idx]);
            }
        }
    } else if constexpr (EPI == 4) {
        ushort* out = (ushort*)out_;
#pragma unroll
        for (int r = 0; r < 4; ++r) {
            int m = m0 + quad * 4 + r;
#pragma unroll
            for (int f = 0; f < 4; ++f) {
                size_t idx = (size_t)m * N + n0 + f * 16 + col;
                float y = acc[f][r] + bs[f];
                out[idx] = f2b(0.5f * y * (1.0f + erff(y * 0.70710678118654752f)));
            }
        }
    } else {
        float* out = (float*)out_;
#pragma unroll
        for (int r = 0; r < 4; ++r) {
            int m = m0 + quad * 4 + r;
#pragma unroll
            for (int f = 0; f < 4; ++f) {
                size_t idx = (size_t)m * N + n0 + f * 16 + col;
                out[idx] = acc[f][r] + bs[f] + b2f(residB[idx]);
            }
        }
    }
}

// ---------------------------------------------------------------------------
// Attention v2: block = (qt, bh) with 16 q-rows; 4 waves split the 2048 kv
// into 512-col chunks. Grid 128 x 24 = 3072 blocks (vs 768) for occupancy.
// Pass 1: partial exp-sums per wave, cross-wave reduce in LDS.
// Pass 2: recompute QK, write P f32 to padded LDS tile, coalesced float4
// copy to attn_out, PV MFMA from LDS A-frags; cross-wave PV reduce in LDS.
// ---------------------------------------------------------------------------
#define PSTRIDE 68   // 64 + 4 f32 pad: breaks power-of-2 bank stride

__global__ __launch_bounds__(256, 6) void attn_kernel(
    const ushort* __restrict__ qb, const ushort* __restrict__ kb,
    const ushort* __restrict__ vb,
    float* __restrict__ attn_out,    // [B,H,S,S] f32
    ushort* __restrict__ vals)       // [B*S, EMB] bf16
{
    const int qt   = blockIdx.x;     // 0..127 (16 q-rows)
    const int bh   = blockIdx.y;     // 0..23
    const int tid  = threadIdx.x;
    const int wave = tid >> 6;
    const int lane = tid & 63;
    const int quad = lane >> 4;
    const int col  = lane & 15;
    const int kv0  = wave * 512;
    const int qrow0 = qt * 16;

    __shared__ __align__(16) float P32[4][16 * PSTRIDE];  // per-wave tiles
    __shared__ float SS[4][16];

    const floatx4 zero = {0.f, 0.f, 0.f, 0.f};

    // Q fragments for the block's 16 rows (same for all waves; L1-served)
    const ushort* qrow = qb + ((size_t)bh * SEQ + qrow0 + col) * HD + quad * 8;
    short8 aq0 = *(const short8*)qrow;
    short8 aq1 = *(const short8*)(qrow + 32);

    const ushort* kbase = kb + (size_t)bh * SEQ * HD + (size_t)(kv0 + col) * HD + quad * 8;
    const ushort* vbase = vb + (size_t)bh * HD * SEQ + (size_t)col * SEQ + kv0 + quad * 8;

    // ---- pass 1: partial row sums of exp over this wave's 512 kv ----
    float sums[4] = {0.f, 0.f, 0.f, 0.f};
    for (int ch = 0; ch < 8; ++ch) {
#pragma unroll
        for (int f = 0; f < 4; ++f) {
            const ushort* kr = kbase + (size_t)(ch * 64 + f * 16) * HD;
            short8 b0 = *(const short8*)kr;
            short8 b1 = *(const short8*)(kr + 32);
            floatx4 t = MFMA16(aq0, b0, zero);
            t = MFMA16(aq1, b1, t);
#pragma unroll
            for (int r = 0; r < 4; ++r) sums[r] += __expf(t[r] * 0.125f);
        }
    }
#pragma unroll
    for (int r = 0; r < 4; ++r) {
        float v = sums[r];
        v += __shfl_xor(v, 1); v += __shfl_xor(v, 2);
        v += __shfl_xor(v, 4); v += __shfl_xor(v, 8);
        sums[r] = v;
    }
    if (col == 0) {
#pragma unroll
        for (int r = 0; r < 4; ++r) SS[wave][quad * 4 + r] = sums[r];
    }
    __syncthreads();
    float rinv[4];
#pragma unroll
    for (int r = 0; r < 4; ++r) {
        int row = quad * 4 + r;
        rinv[r] = 1.0f / (SS[0][row] + SS[1][row] + SS[2][row] + SS[3][row]);
    }

    // ---- pass 2: P write (LDS -> coalesced global) + PV ----
    const size_t gbase = (size_t)bh * SEQ + qrow0;
    floatx4 acco[4] = {zero, zero, zero, zero};
    for (int ch = 0; ch < 8; ++ch) {
#pragma unroll
        for (int f = 0; f < 4; ++f) {
            const ushort* kr = kbase + (size_t)(ch * 64 + f * 16) * HD;
            short8 b0 = *(const short8*)kr;
            short8 b1 = *(const short8*)(kr + 32);
            floatx4 t = MFMA16(aq0, b0, zero);
            t = MFMA16(aq1, b1, t);
#pragma unroll
            for (int r = 0; r < 4; ++r) {
                float p = __expf(t[r] * 0.125f) * rinv[r];
                P32[wave][(quad * 4 + r) * PSTRIDE + f * 16 + col] = p;
            }
        }
        // coalesced copy: 4 iters x (4 rows x 256 B contiguous)
#pragma unroll
        for (int it = 0; it < 4; ++it) {
            int row = it * 4 + quad;
            float4 v = *(const float4*)&P32[wave][row * PSTRIDE + col * 4];
            *(float4*)&attn_out[(gbase + row) * SEQ + kv0 + ch * 64 + col * 4] = v;
        }
        // PV: A-frags from LDS (f32 -> packed bf16 cvt)
        const float* pl = &P32[wave][col * PSTRIDE + quad * 8];
        float4 pa = *(const float4*)pl;
        float4 pb = *(const float4*)(pl + 4);
        float4 pc = *(const float4*)(pl + 32);
        float4 pd = *(const float4*)(pl + 36);
        ushort2 c0 = f2b2(pa.x, pa.y), c1 = f2b2(pa.z, pa.w);
        ushort2 c2 = f2b2(pb.x, pb.y), c3 = f2b2(pb.z, pb.w);
        ushort2 c4 = f2b2(pc.x, pc.y), c5 = f2b2(pc.z, pc.w);
        ushort2 c6 = f2b2(pd.x, pd.y), c7 = f2b2(pd.z, pd.w);
        short8 ap0 = {(short)c0.x, (short)c0.y, (short)c1.x, (short)c1.y,
                      (short)c2.x, (short)c2.y, (short)c3.x, (short)c3.y};
        short8 ap1 = {(short)c4.x, (short)c4.y, (short)c5.x, (short)c5.y,
                      (short)c6.x, (short)c6.y, (short)c7.x, (short)c7.y};
#pragma unroll
        for (int f = 0; f < 4; ++f) {
            const ushort* vr = vbase + (size_t)(f * 16) * SEQ + ch * 64;
            short8 b0 = *(const short8*)vr;
            short8 b1 = *(const short8*)(vr + 32);
            acco[f] = MFMA16(ap0, b0, acco[f]);
            acco[f] = MFMA16(ap1, b1, acco[f]);
        }
    }

    // ---- cross-wave PV reduction via LDS (reuse P32) ----
    __syncthreads();   // everyone done with pass-2 tiles
#pragma unroll
    for (int f = 0; f < 4; ++f)
#pragma unroll
        for (int r = 0; r < 4; ++r)
            P32[wave][(quad * 4 + r) * PSTRIDE + f * 16 + col] = acco[f][r];
    __syncthreads();

    {
        int row = tid >> 4;            // 0..15
        int d0  = (tid & 15) * 4;      // 0..60
        int off = row * PSTRIDE + d0;
        float4 s0 = *(const float4*)&P32[0][off];
        float4 s1 = *(const float4*)&P32[1][off];
        float4 s2 = *(const float4*)&P32[2][off];
        float4 s3 = *(const float4*)&P32[3][off];
        float4 s;
        s.x = s0.x + s1.x + s2.x + s3.x;
        s.y = s0.y + s1.y + s2.y + s3.y;
        s.z = s0.z + s1.z + s2.z + s3.z;
        s.w = s0.w + s1.w + s2.w + s3.w;
        ushort2 u0 = f2b2(s.x, s.y), u1 = f2b2(s.z, s.w);
        ushort4 o; o.x = u0.x; o.y = u0.y; o.z = u1.x; o.w = u1.y;
        const int b = bh / NH, h = bh - b * NH;
        size_t idx = ((size_t)(b * SEQ + qrow0 + row)) * EMB + h * HD + d0;
        *(ushort4*)&vals[idx] = o;
    }
}

// ---------------------------------------------------------------------------
// LayerNorm over 1280, one block (256 threads) per row.
// ---------------------------------------------------------------------------
__global__ __launch_bounds__(256) void ln_kernel(
    const ushort* __restrict__ x, const float* __restrict__ g,
    const float* __restrict__ bt, ushort* __restrict__ out)
{
    const int row = blockIdx.x;
    const int tid = threadIdx.x;
    const ushort* xr = x + (size_t)row * PLM;

    float xs[5];
    float s = 0.f, s2 = 0.f;
#pragma unroll
    for (int i = 0; i < 5; ++i) {
        float v = b2f(xr[tid + i * 256]);
        xs[i] = v; s += v; s2 += v * v;
    }
#pragma unroll
    for (int off = 1; off < 64; off <<= 1) {
        s  += __shfl_xor(s,  off);
        s2 += __shfl_xor(s2, off);
    }
    __shared__ float red[8];
    const int wave = tid >> 6, lane = tid & 63;
    if (lane == 0) { red[wave] = s; red[4 + wave] = s2; }
    __syncthreads();
    s  = red[0] + red[1] + red[2] + red[3];
    s2 = red[4] + red[5] + red[6] + red[7];
    float mean = s * (1.0f / PLM);
    float var  = s2 * (1.0f / PLM) - mean * mean;
    float rstd = rsqrtf(var + 1e-5f);

    ushort* orow = out + (size_t)row * PLM;
#pragma unroll
    for (int i = 0; i < 5; ++i) {
        int c = tid + i * 256;
        orow[c] = f2b((xs[i] - mean) * rstd * g[c] + bt[c]);
    }
}

// ---------------------------------------------------------------------------
extern "C" void kernel_launch(void* const* d_in, const int* in_sizes, int n_in,
                              void* d_out, int out_size, void* d_ws, size_t ws_size,
                              hipStream_t stream)
{
    const float* s_repre = (const float*)d_in[0];
    const float* plm     = (const float*)d_in[1];
    const float* Wq = (const float*)d_in[2];
    const float* bq = (const float*)d_in[3];
    const float* Wk = (const float*)d_in[4];
    const float* bk = (const float*)d_in[5];
    const float* Wv = (const float*)d_in[6];
    const float* bv = (const float*)d_in[7];
    const float* Wo = (const float*)d_in[8];
    const float* bo = (const float*)d_in[9];
    const float* ln_g = (const float*)d_in[10];
    const float* ln_b = (const float*)d_in[11];
    const float* Wd = (const float*)d_in[12];
    const float* bd = (const float*)d_in[13];
    const float* Wu = (const float*)d_in[14];
    const float* bu = (const float*)d_in[15];

    // workspace layout (bf16 elements)
    ushort* ws    = (ushort*)d_ws;
    ushort* q_buf = ws;                          // [B,H,S,D]
    ushort* k_buf = q_buf + (size_t)MROWS * EMB;
    ushort* v_buf = k_buf + (size_t)MROWS * EMB; // [B,H,D,S]
    ushort* vals  = v_buf + (size_t)MROWS * EMB; // [B*S, EMB]
    ushort* x_buf = vals  + (size_t)MROWS * EMB; // [B*S, PLM]
    ushort* resid = x_buf + (size_t)MROWS * PLM; // [B*S, PLM]
    ushort* h_buf = resid + (size_t)MROWS * PLM; // [B*S, FFN]
    // bf16 copies of f32 inputs — contiguous, in cvt_all segment order
    ushort* sr_b  = h_buf + (size_t)MROWS * FFN;
    ushort* plm_b = sr_b  + (size_t)MROWS * 128;
    ushort* Wq_b  = plm_b + (size_t)MROWS * PLM;
    ushort* Wk_b  = Wq_b  + (size_t)EMB * PLM;
    ushort* Wv_b  = Wk_b  + (size_t)EMB * 128;
    ushort* Wo_b  = Wv_b  + (size_t)EMB * 128;
    ushort* Wd_b  = Wo_b  + (size_t)PLM * EMB;
    ushort* Wu_b  = Wd_b  + (size_t)FFN * PLM;

    float* out_main = (float*)d_out;                        // [B*S, PLM]
    float* attn_out = out_main + (size_t)MROWS * PLM;       // [B,H,S,S]

    dim3 blk(256);

    // one fused conversion pass over all f32 inputs
    cvt_all<<<dim3(CV7 / 256), blk, 0, stream>>>(
        s_repre, plm, Wq, Wk, Wv, Wo, Wd, Wu, sr_b);

    // q = RoPE(plm @ Wq^T + bq)            -> [B,H,S,D]
    gemm_nt<1><<<dim3(MROWS / 64, EMB / 64), blk, 0, stream>>>(
        plm_b, Wq_b, bq, nullptr, nullptr, q_buf, MROWS, EMB, PLM);
    // k = RoPE(s_repre @ Wk^T + bk)        -> [B,H,S,D]
    gemm_nt<1><<<dim3(MROWS / 64, EMB / 64), blk, 0, stream>>>(
        sr_b, Wk_b, bk, nullptr, nullptr, k_buf, MROWS, EMB, 128);
    // v = s_repre @ Wv^T + bv              -> [B,H,D,S]
    gemm_nt<2><<<dim3(MROWS / 64, EMB / 64), blk, 0, stream>>>(
        sr_b, Wv_b, bv, nullptr, nullptr, v_buf, MROWS, EMB, 128);

    // attention probs (f32, to d_out) + vals (bf16)
    attn_kernel<<<dim3(SEQ / 16, BATCH * NH), blk, 0, stream>>>(
        q_buf, k_buf, v_buf, attn_out, vals);

    // x = vals @ Wo^T + bo + plm           -> x_buf (bf16)
    gemm_nt<3><<<dim3(MROWS / 64, PLM / 64), blk, 0, stream>>>(
        vals, Wo_b, bo, plm, nullptr, x_buf, MROWS, PLM, EMB);

    // resid = LayerNorm(x)
    ln_kernel<<<dim3(MROWS), blk, 0, stream>>>(x_buf, ln_g, ln_b, resid);

    // h = gelu(resid @ Wd^T + bd)
    gemm_nt<4><<<dim3(MROWS / 64, FFN / 64), blk, 0, stream>>>(
        resid, Wd_b, bd, nullptr, nullptr, h_buf, MROWS, FFN, PLM);

    // out = h @ Wu^T + bu + resid          -> d_out (f32)
    gemm_nt<5><<<dim3(MROWS / 64, PLM / 64), blk, 0, stream>>>(
        h_buf, Wu_b, bu, nullptr, resid, out_main, MROWS, PLM, FFN);
}